// Round 10
// baseline (624.901 us; speedup 1.0000x reference)
//
#include <hip/hip_runtime.h>
#include <hip/hip_bf16.h>
#include <cstdint>
#include <cstddef>

// v11 — split-K attention: keys split 2-way across blocks (grid 1024 -> 4 blk/CU,
// 4 waves/SIMD, double v7's TLP at identical per-wave cost). Pass1/pass2 are
// separate kernels; partials combined in rms. Od1 reuses d_out (overwritten by
// the final GEMM). attn body = v7's proven sP/16x16x32 path, single-buffered.

typedef __attribute__((ext_vector_type(8))) short short8;
typedef __attribute__((ext_vector_type(4))) short short4v;
typedef __attribute__((ext_vector_type(4))) float float4v;

#define S_LEN 2048
#define NHEADS 16
#define DHEAD 128

__device__ __forceinline__ short f2bf(float f) {
    union { float f; unsigned u; } v; v.f = f;
    unsigned r = (v.u + 0x7fffu + ((v.u >> 16) & 1u)) >> 16;
    return (short)(r & 0xffffu);
}
// round-half-up bf16 pack: 2 VALU ops, error <= 1 ulp vs RNE
__device__ __forceinline__ short f2bf_rhu(float f) {
    union { float f; unsigned u; } v; v.f = f;
    return (short)((v.u + 0x8000u) >> 16);
}

typedef __attribute__((address_space(1))) void gvoid;
typedef __attribute__((address_space(3))) void lvoid;

__device__ __forceinline__ void gl_lds16(const void* g, void* l) {
    __builtin_amdgcn_global_load_lds((gvoid*)g, (lvoid*)l, 16, 0, 0);
}

__device__ __forceinline__ float4v mfma16(short8 a, short8 b, float4v c) {
    return __builtin_amdgcn_mfma_f32_16x16x32_bf16(a, b, c, 0, 0, 0);
}

// swizzled LDS tile addressing: tiles are arrays of 16B chunks.
__device__ __forceinline__ const char* lds8(const short* base, int row, int ch) {
    return (const char*)base + (((row << 3) + (ch ^ (row & 7))) << 4);
}
__device__ __forceinline__ const char* lds16a(const short* base, int row, int ch) {
    return (const char*)base + (((row << 4) + (ch ^ (row & 15))) << 4);
}
// lds4: 4-chunk rows (32 bf16), swizzle (row>>1)&3
__device__ __forceinline__ const char* lds4(const short* base, int row, int ch) {
    return (const char*)base + (((row << 2) + (ch ^ ((row >> 1) & 3))) << 4);
}

// ---------------- elementwise fp32 -> bf16 ----------------
__global__ __launch_bounds__(256)
void cvt_bf16(const float* __restrict__ X, short* __restrict__ Y) {
    size_t i = ((size_t)blockIdx.x * 256 + threadIdx.x) * 4;
    float4v v = *(const float4v*)(X + i);
    short4v o;
#pragma unroll
    for (int j = 0; j < 4; ++j) o[j] = f2bf(v[j]);
    *(short4v*)(Y + i) = o;
}

// ---------------- W[K][N] fp32 -> Wt[N][K] bf16, optional pre-scale ----------------
__global__ __launch_bounds__(256)
void tposew(const float* __restrict__ W, short* __restrict__ Wt, int K, int N, float scale) {
    __shared__ float t[32][33];
    int bx = blockIdx.x, by = blockIdx.y;
    int tx = threadIdx.x & 31, ty = threadIdx.x >> 5;
#pragma unroll
    for (int i = 0; i < 32; i += 8)
        t[ty + i][tx] = W[(size_t)(by * 32 + ty + i) * N + bx * 32 + tx];
    __syncthreads();
#pragma unroll
    for (int i = 0; i < 32; i += 8)
        Wt[(size_t)(bx * 32 + ty + i) * K + by * 32 + tx] = f2bf(t[tx][ty + i] * scale);
}

// ---------------- BT-GEMM: C[M][N] = A[M][K] * Bt[N][K]^T (bf16 in, f32 acc) ----
// (round-0 proven single-buffer form)
template <int MODE>
__global__ __launch_bounds__(256, 2)
void gemm_bt(const short* __restrict__ A, const short* __restrict__ Bt,
             void* __restrict__ Cv, int M, int N, int K) {
    __shared__ short sA[128 * 64];
    __shared__ short sB[128 * 64];
    const int tid = threadIdx.x;
    const int wid = tid >> 6, lane = tid & 63;
    const int quad = lane >> 4, l15 = lane & 15;
    const int n0 = blockIdx.x * 128, m0 = blockIdx.y * 128;
    const int wm = (wid & 1) * 64, wn = (wid >> 1) * 64;
    float4v acc[4][4] = {};
    for (int k0 = 0; k0 < K; k0 += 64) {
        __syncthreads();
#pragma unroll
        for (int i = 0; i < 4; ++i) {
            int c = i * 256 + tid;
            int row = c >> 3, kc = c & 7, g = kc ^ (row & 7);
            int lb = ((i << 8) + (wid << 6)) << 4;
            gl_lds16(A + (size_t)(m0 + row) * K + k0 + g * 8, (char*)(void*)sA + lb);
            gl_lds16(Bt + (size_t)(n0 + row) * K + k0 + g * 8, (char*)(void*)sB + lb);
        }
        __syncthreads();
#pragma unroll
        for (int ks = 0; ks < 2; ++ks) {
            short8 af[4], bf[4];
#pragma unroll
            for (int t = 0; t < 4; ++t) {
                int q = ks * 4 + quad;
                af[t] = *(const short8*)lds8(sA, wm + t * 16 + l15, q);
                bf[t] = *(const short8*)lds8(sB, wn + t * 16 + l15, q);
            }
#pragma unroll
            for (int mt = 0; mt < 4; ++mt)
#pragma unroll
                for (int nt = 0; nt < 4; ++nt)
                    acc[mt][nt] = mfma16(af[mt], bf[nt], acc[mt][nt]);
        }
    }
#pragma unroll
    for (int mt = 0; mt < 4; ++mt)
#pragma unroll
        for (int nt = 0; nt < 4; ++nt) {
            int rbase = m0 + wm + mt * 16 + quad * 4;
            int col = n0 + wn + nt * 16 + l15;
            if (MODE == 0) {
                short* Cb = (short*)Cv;
#pragma unroll
                for (int i = 0; i < 4; ++i)
                    Cb[(size_t)(rbase + i) * N + col] = f2bf(acc[mt][nt][i]);
            } else if (MODE == 1) {
                float* Cf = (float*)Cv;
#pragma unroll
                for (int i = 0; i < 4; ++i)
                    Cf[(size_t)(rbase + i) * N + col] = acc[mt][nt][i];
            } else {
                short4v pk;
#pragma unroll
                for (int i = 0; i < 4; ++i) pk[i] = f2bf(acc[mt][nt][i]);
                int bb = rbase >> 11, s = rbase & 2047;
                short* Cb = (short*)Cv;
                *(short4v*)(Cb + ((size_t)(bb * 2048 + col) * 2048 + s)) = pk;
            }
        }
}

// Shared block-index decode for the split-K attention kernels.
// grid 1024: xcd = xb&7 (8 XCDs), 4 bh per XCD, then (qx, half).
__device__ __forceinline__ void attn_decode(int xb, int wid, int& b, int& h,
                                            int& half, int& wrow) {
    int local = xb >> 3;
    int bh = (xb & 7) * 4 + (local >> 5);
    int rem = local & 31;
    int qx = rem >> 1;
    half = rem & 1;
    b = bh >> 4; h = bh & 15;
    wrow = qx * 128 + wid * 32;
}

// ---------------- attention pass 1: partial l1/l2 over one key-half ----------------
// Swapped QK^T (v7): mfma(K,Q) -> lane(quad,l15) holds S[key=kb*16+quad*4+r][q=l15];
// l1/l2 accumulate in-lane over (kb,r); cross-key reduce = xor16+xor32.
// Single-buffered K tiles (8KB x2 LDS); 1024 blocks -> 4 blocks/CU.
__global__ __launch_bounds__(256, 2)
void attn_p1(const short* __restrict__ Q, const short* __restrict__ Kq,
             float* __restrict__ Lp1, float* __restrict__ Lp2) {
    __shared__ short sK1[32 * 128];  // 8 KB
    __shared__ short sK2[32 * 128];  // 8 KB

    const int tid = threadIdx.x;
    const int wid = tid >> 6, lane = tid & 63;
    const int quad = lane >> 4, l15 = lane & 15;
    int b, h, half, wrow;
    attn_decode(blockIdx.x, wid, b, h, half, wrow);

    short8 q1f[2][4], q2f[2][4];
    {
        const short* qb = Q + (size_t)(b * S_LEN + wrow) * 4096 + h * 256;
#pragma unroll
        for (int mt = 0; mt < 2; ++mt)
#pragma unroll
            for (int ks = 0; ks < 4; ++ks) {
                const short* p = qb + (size_t)(mt * 16 + l15) * 4096 + ks * 32 + quad * 8;
                q1f[mt][ks] = *(const short8*)p;
                q2f[mt][ks] = *(const short8*)(p + 128);
            }
    }
    const short* k1g = Kq + (size_t)(b * S_LEN + half * 1024) * 4096 + h * 256;
    const short* k2g = k1g + 128;

    int offK[2], lbs[2];
#pragma unroll
    for (int i = 0; i < 2; ++i) {
        int c = i * 256 + tid;
        int row = c >> 4, kc = c & 15;
        offK[i] = row * 4096 + ((kc ^ (row & 15)) << 3);
        lbs[i] = ((i << 8) + (wid << 6)) << 4;
    }

    float l1a[2] = {}, l2a[2] = {};
    for (int ti = 0; ti < 32; ++ti) {
        __syncthreads();  // WAR: previous tile's reads done
        const short* k1b = k1g + (size_t)ti * 32 * 4096;
        const short* k2b = k2g + (size_t)ti * 32 * 4096;
#pragma unroll
        for (int i = 0; i < 2; ++i) {
            gl_lds16(k1b + offK[i], (char*)(void*)sK1 + lbs[i]);
            gl_lds16(k2b + offK[i], (char*)(void*)sK2 + lbs[i]);
        }
        __syncthreads();  // visibility
#pragma unroll
        for (int kb = 0; kb < 2; ++kb) {
            float4v s1[2] = {}, s2[2] = {};
            int krow = kb * 16 + l15;
            __builtin_amdgcn_s_setprio(1);
#pragma unroll
            for (int ks = 0; ks < 4; ++ks) {
                int q = ks * 4 + quad;
                short8 kf1 = *(const short8*)lds16a(sK1, krow, q);
                short8 kf2 = *(const short8*)lds16a(sK2, krow, q);
#pragma unroll
                for (int qb = 0; qb < 2; ++qb) {
                    s1[qb] = mfma16(kf1, q1f[qb][ks], s1[qb]);
                    s2[qb] = mfma16(kf2, q2f[qb][ks], s2[qb]);
                }
            }
            __builtin_amdgcn_s_setprio(0);
#pragma unroll
            for (int qb = 0; qb < 2; ++qb)
#pragma unroll
                for (int r = 0; r < 4; ++r) {
                    l1a[qb] += __builtin_amdgcn_exp2f(s1[qb][r]);
                    l2a[qb] += __builtin_amdgcn_exp2f(s2[qb][r]);
                }
        }
    }
#pragma unroll
    for (int qb = 0; qb < 2; ++qb) {
        l1a[qb] += __shfl_xor(l1a[qb], 16, 64);
        l1a[qb] += __shfl_xor(l1a[qb], 32, 64);
        l2a[qb] += __shfl_xor(l2a[qb], 16, 64);
        l2a[qb] += __shfl_xor(l2a[qb], 32, 64);
    }
    if (quad == 0) {
#pragma unroll
        for (int qb = 0; qb < 2; ++qb) {
            int grow = b * S_LEN + wrow + qb * 16 + l15;
            Lp1[half * 4096 + grow] = l1a[qb];
            Lp2[half * 4096 + grow] = l2a[qb];
        }
    }
}

// ---------------- attention pass 2: partial O/lda over one key-half ----------------
// v7's proven body (sP + 16x16x32 PV). Reads combined l1/l2 from Lp; writes raw
// partial O (no normalize) and partial lda. LDS 32KB single-buffered -> 4 blk/CU.
__global__ __launch_bounds__(256, 2)
void attn_p2(const short* __restrict__ Q, const short* __restrict__ Kq,
             const short* __restrict__ Vt, const float* __restrict__ lam,
             const float* __restrict__ Lp1, const float* __restrict__ Lp2,
             float* __restrict__ Od0, float* __restrict__ Od1,
             float* __restrict__ Ld) {
    __shared__ short sK1[32 * 128];   // 8 KB
    __shared__ short sK2[32 * 128];   // 8 KB
    __shared__ short sV[128 * 32];    // 8 KB
    __shared__ short sP[4][32 * 32];  // 8 KB (2 KB/wave)

    const int tid = threadIdx.x;
    const int wid = tid >> 6, lane = tid & 63;
    const int quad = lane >> 4, l15 = lane & 15;
    int b, h, half, wrow;
    attn_decode(blockIdx.x, wid, b, h, half, wrow);

    const float lamh = lam[h];
    const float C0 = 0.5287663729448977f;  // log2(log2(e))

    short8 q1f[2][4], q2f[2][4];
    {
        const short* qb = Q + (size_t)(b * S_LEN + wrow) * 4096 + h * 256;
#pragma unroll
        for (int mt = 0; mt < 2; ++mt)
#pragma unroll
            for (int ks = 0; ks < 4; ++ks) {
                const short* p = qb + (size_t)(mt * 16 + l15) * 4096 + ks * 32 + quad * 8;
                q1f[mt][ks] = *(const short8*)p;
                q2f[mt][ks] = *(const short8*)(p + 128);
            }
    }
    // combined normalizers from pass-1 partials
    const float llam = __log2f(lamh);
    float c1[2], c2[2];
#pragma unroll
    for (int qb = 0; qb < 2; ++qb) {
        int grow = b * S_LEN + wrow + qb * 16 + l15;
        float l1 = Lp1[grow] + Lp1[4096 + grow];
        float l2 = Lp2[grow] + Lp2[4096 + grow];
        c1[qb] = C0 - __log2f(l1);
        c2[qb] = C0 + llam - __log2f(l2);
    }

    const short* k1g = Kq + (size_t)(b * S_LEN + half * 1024) * 4096 + h * 256;
    const short* k2g = k1g + 128;
    const short* vg = Vt + (size_t)(b * NHEADS + h) * DHEAD * S_LEN + half * 1024;

    int offK[2], offV[2], lbs[2];
#pragma unroll
    for (int i = 0; i < 2; ++i) {
        int c = i * 256 + tid;
        int row = c >> 4, kc = c & 15;
        offK[i] = row * 4096 + ((kc ^ (row & 15)) << 3);
        int dh = c >> 2, vc = c & 3;
        offV[i] = dh * 2048 + ((vc ^ ((dh >> 1) & 3)) << 3);
        lbs[i] = ((i << 8) + (wid << 6)) << 4;
    }

    float lda[2] = {};
    float4v oacc[2][8] = {};

    for (int ti = 0; ti < 32; ++ti) {
        __syncthreads();  // WAR: previous tile's reads done
        {
            const short* k1b = k1g + (size_t)ti * 32 * 4096;
            const short* k2b = k2g + (size_t)ti * 32 * 4096;
            const short* vb = vg + ti * 32;
#pragma unroll
            for (int i = 0; i < 2; ++i) {
                gl_lds16(k1b + offK[i], (char*)(void*)sK1 + lbs[i]);
                gl_lds16(k2b + offK[i], (char*)(void*)sK2 + lbs[i]);
                gl_lds16(vb + offV[i], (char*)(void*)sV + lbs[i]);
            }
        }
        __syncthreads();  // visibility
        short* sPw = sP[wid];
#pragma unroll
        for (int kb = 0; kb < 2; ++kb) {
            float4v s1[2] = {}, s2[2] = {};
            int krow = kb * 16 + l15;
            __builtin_amdgcn_s_setprio(1);
#pragma unroll
            for (int ks = 0; ks < 4; ++ks) {
                int q = ks * 4 + quad;
                short8 kf1 = *(const short8*)lds16a(sK1, krow, q);
                short8 kf2 = *(const short8*)lds16a(sK2, krow, q);
#pragma unroll
                for (int qb = 0; qb < 2; ++qb) {
                    s1[qb] = mfma16(kf1, q1f[qb][ks], s1[qb]);
                    s2[qb] = mfma16(kf2, q2f[qb][ks], s2[qb]);
                }
            }
            __builtin_amdgcn_s_setprio(0);
#pragma unroll
            for (int qb = 0; qb < 2; ++qb) {
                short4v pk;
#pragma unroll
                for (int r = 0; r < 4; ++r) {
                    float u1 = __builtin_amdgcn_exp2f(s1[qb][r] + c1[qb]);
                    float u2 = __builtin_amdgcn_exp2f(s2[qb][r] + c2[qb]);
                    float e = __builtin_amdgcn_exp2f(u1 - u2);
                    lda[qb] += e;
                    pk[r] = f2bf_rhu(e);
                }
                // v7 layout: row = qb*16+l15; chunk p = kb*2+(quad>>1), swz p^(l15&3)
                int byte = ((qb << 4) + l15) * 64 +
                           ((((kb << 1) + (quad >> 1)) ^ (l15 & 3)) << 4) +
                           ((quad & 1) << 3);
                *(short4v*)((char*)sPw + byte) = pk;
            }
        }
        // PV: sP wave-private; sV gated by the barrier pair
        __builtin_amdgcn_s_setprio(1);
        {
            short8 pa[2];
#pragma unroll
            for (int qb = 0; qb < 2; ++qb)
                pa[qb] = *(const short8*)((const char*)sPw + ((qb << 4) + l15) * 64 +
                                          ((quad ^ (l15 & 3)) << 4));
#pragma unroll
            for (int nt = 0; nt < 8; ++nt) {
                short8 vbf = *(const short8*)lds4(sV, nt * 16 + l15, quad);
#pragma unroll
                for (int qb = 0; qb < 2; ++qb)
                    oacc[qb][nt] = mfma16(pa[qb], vbf, oacc[qb][nt]);
            }
        }
        __builtin_amdgcn_s_setprio(0);
    }

    // partial lda per q-row (in-lane over keys; reduce across quads)
#pragma unroll
    for (int qb = 0; qb < 2; ++qb) {
        lda[qb] += __shfl_xor(lda[qb], 16, 64);
        lda[qb] += __shfl_xor(lda[qb], 32, 64);
    }
    if (quad == 0) {
#pragma unroll
        for (int qb = 0; qb < 2; ++qb)
            Ld[half * 4096 + b * S_LEN + wrow + qb * 16 + l15] = lda[qb];
    }
    // raw partial O (normalization deferred to rms)
    float* Odh = half ? Od1 : Od0;
#pragma unroll
    for (int qb = 0; qb < 2; ++qb)
#pragma unroll
        for (int nt = 0; nt < 8; ++nt)
#pragma unroll
            for (int r = 0; r < 4; ++r) {
                int row = b * S_LEN + wrow + qb * 16 + quad * 4 + r;
                int col = h * DHEAD + nt * 16 + l15;
                Odh[(size_t)row * 2048 + col] = oacc[qb][nt][r];
            }
}

// ---------------- combine + RMS norm + scale * (1 - mean(lam)), f32 -> bf16 --------
__global__ __launch_bounds__(256)
void rms_kernel(const float* __restrict__ Od0, const float* __restrict__ Od1,
                const float* __restrict__ Ld, const float* __restrict__ gs,
                const float* __restrict__ lam, short* __restrict__ Y) {
    int row = blockIdx.x, tid = threadIdx.x;
    float inv = 1.0f / (Ld[row] + Ld[4096 + row]);
    const float* x0 = Od0 + (size_t)row * 2048 + tid * 8;
    const float* x1 = Od1 + (size_t)row * 2048 + tid * 8;
    float4v a0 = *(const float4v*)(x0);
    float4v a1 = *(const float4v*)(x0 + 4);
    float4v b0 = *(const float4v*)(x1);
    float4v b1 = *(const float4v*)(x1 + 4);
    float4v v0, v1;
#pragma unroll
    for (int j = 0; j < 4; ++j) {
        v0[j] = (a0[j] + b0[j]) * inv;
        v1[j] = (a1[j] + b1[j]) * inv;
    }
    float ss = 0;
#pragma unroll
    for (int j = 0; j < 4; ++j) ss += v0[j] * v0[j] + v1[j] * v1[j];
#pragma unroll
    for (int off = 32; off > 0; off >>= 1) ss += __shfl_xor(ss, off, 64);
    __shared__ float wsum[4];
    if ((tid & 63) == 0) wsum[tid >> 6] = ss;
    __syncthreads();
    float tot = wsum[0] + wsum[1] + wsum[2] + wsum[3];
    float lm = 0;
#pragma unroll
    for (int i = 0; i < 16; ++i) lm += lam[i];
    float f = (1.0f - lm * (1.0f / 16.0f)) * rsqrtf(tot * (1.0f / 2048.0f) + 1e-6f);
    float4v g0 = *(const float4v*)(gs + tid * 8);
    float4v g1 = *(const float4v*)(gs + tid * 8 + 4);
    short4v o0, o1;
#pragma unroll
    for (int j = 0; j < 4; ++j) {
        o0[j] = f2bf(v0[j] * f * g0[j]);
        o1[j] = f2bf(v1[j] * f * g1[j]);
    }
    *(short4v*)(Y + (size_t)row * 2048 + tid * 8) = o0;
    *(short4v*)(Y + (size_t)row * 2048 + tid * 8 + 4) = o1;
}

extern "C" void kernel_launch(void* const* d_in, const int* in_sizes, int n_in,
                              void* d_out, int out_size, void* d_ws, size_t ws_size,
                              hipStream_t stream) {
    const float* x = (const float*)d_in[0];
    const float* Wq = (const float*)d_in[1];
    const float* Wk = (const float*)d_in[2];
    const float* Wv = (const float*)d_in[3];
    const float* Wo = (const float*)d_in[4];
    const float* nsc = (const float*)d_in[5];
    const float* lam = (const float*)d_in[6];
    float* out = (float*)d_out;
    (void)in_sizes; (void)n_in; (void)out_size; (void)ws_size;

    char* ws = (char*)d_ws;
    short* Xb  = (short*)(ws);                 // 16 MiB  [4096][2048]   (dead after gemms)
    short* Wqt = (short*)(ws + 16777216);      // 16 MiB                 (dead after gemms)
    short* Wkt = (short*)(ws + 33554432);      // 16 MiB                 (dead after gemms)
    short* Wvt = (short*)(ws + 50331648);      //  8 MiB                 (dead after gemms)
    short* Wot = (short*)(ws + 58720256);      //  8 MiB  (read by FINAL gemm — never overlaid)
    short* Cq  = (short*)(ws + 67108864);      // 32 MiB  [4096][4096]   (read p1,p2)
    short* Ck  = (short*)(ws + 100663296);     // 32 MiB  [4096][4096]   (read p1,p2)
    short* Vt  = (short*)(ws + 134217728);     // 16 MiB  [2][16][128][2048] (read p2)
    // Overlays (all regions dead by the time they're written):
    float* Od0 = (float*)(ws);                 // 32 MiB over Xb+Wqt  (written p2, read rms)
    float* Od1 = out;                          // 32 MiB: d_out reused; final gemm overwrites
    float* Lp1 = (float*)(ws + 50331648);      // 32 KiB over Wvt     (written p1, read p2)
    float* Lp2 = (float*)(ws + 50331648 + 32768);
    float* Ld  = (float*)(ws + 50331648 + 65536);
    short* Nrm = (short*)(ws + 33554432);      // 16 MiB over Wkt     (written rms, read final gemm)

    // QKSCALE = (1/sqrt(128)) * log2(e), folded into Wq so scores exit the MFMA
    // in log2-domain
    const float QKSCALE = 0.12752965213246994f;

    cvt_bf16<<<8192, 256, 0, stream>>>(x, Xb);
    tposew<<<dim3(128, 64), 256, 0, stream>>>(Wq, Wqt, 2048, 4096, QKSCALE);
    tposew<<<dim3(128, 64), 256, 0, stream>>>(Wk, Wkt, 2048, 4096, 1.0f);
    tposew<<<dim3(64, 64), 256, 0, stream>>>(Wv, Wvt, 2048, 2048, 1.0f);
    tposew<<<dim3(64, 64), 256, 0, stream>>>(Wo, Wot, 2048, 2048, 1.0f);

    gemm_bt<0><<<dim3(32, 32), 256, 0, stream>>>(Xb, Wqt, (void*)Cq, 4096, 4096, 2048);
    gemm_bt<0><<<dim3(32, 32), 256, 0, stream>>>(Xb, Wkt, (void*)Ck, 4096, 4096, 2048);
    gemm_bt<2><<<dim3(16, 32), 256, 0, stream>>>(Xb, Wvt, (void*)Vt, 4096, 2048, 2048);

    attn_p1<<<dim3(1024), 256, 0, stream>>>(Cq, Ck, Lp1, Lp2);
    attn_p2<<<dim3(1024), 256, 0, stream>>>(Cq, Ck, Vt, lam, Lp1, Lp2, Od0, Od1, Ld);
    rms_kernel<<<4096, 256, 0, stream>>>(Od0, Od1, Ld, nsc, lam, Nrm);
    gemm_bt<1><<<dim3(16, 32), 256, 0, stream>>>(Nrm, Wot, (void*)out, 4096, 2048, 2048);
}